// Round 6
// baseline (380.912 us; speedup 1.0000x reference)
//
#include <hip/hip_runtime.h>
#include <math.h>

#define TT 8192
#define HH 768
#define II 3072
#define EE 8
#define MAXT 72
#define NCVT 768    // X convert blocks: 8192 f32 each
#define NXPT 2304   // 128x64 transpose tiles per weight tensor: 8 * (768/128)*(3072/64)

typedef short bf16x8 __attribute__((ext_vector_type(8)));
typedef float f32x4 __attribute__((ext_vector_type(4)));

__device__ __forceinline__ ushort f2b(float f) {
    union { float f; unsigned int i; } x; x.f = f;
    unsigned int r = x.i + 0x7fffu + ((x.i >> 16) & 1u);
    return (ushort)(r >> 16);
}

__device__ __forceinline__ void glds16(const ushort* g, ushort* l) {
    __builtin_amdgcn_global_load_lds(
        (const __attribute__((address_space(1))) void*)g,
        (__attribute__((address_space(3))) void*)l, 16, 0, 0);
}

// A&S 7.1.26 erf (max abs err 1.5e-7) -> exact-GELU
__device__ __forceinline__ float fast_gelu(float v) {
    float x = v * 0.70710678118654752f;
    float ax = fabsf(x);
    float t = __builtin_amdgcn_rcpf(__builtin_fmaf(0.3275911f, ax, 1.0f));
    float p = __builtin_fmaf(t, 1.061405429f, -1.453152027f);
    p = __builtin_fmaf(t, p, 1.421413741f);
    p = __builtin_fmaf(t, p, -0.284496736f);
    p = __builtin_fmaf(t, p, 0.254829592f);
    p = p * t;
    float e = __expf(-ax * ax);
    float erf_abs = 1.0f - p * e;
    float er = (x < 0.0f) ? -erf_abs : erf_abs;
    return 0.5f * v * (1.0f + er);
}

// ---- 128x64 transpose+convert tile: src f32 [.][C] rows r0..r0+128, cols c0..c0+64
//      -> dst bf16 [C][R] rows c0..c0+64 (each 256B contiguous write)
// LDS T: ushort[128][70] (pad 70 -> both phases ~2-way bank-conflict-free)
__device__ __forceinline__ void xpose_tile128(const float* __restrict__ src,
                                              ushort* __restrict__ dst,
                                              int R, int C, int r0, int c0,
                                              int tid, ushort* __restrict__ T) {
    int lr = tid >> 1, half = tid & 1;
    const float* sp = src + (size_t)(r0 + lr) * C + c0 + half * 32;
    ushort* tp = T + lr * 70 + half * 32;
#pragma unroll
    for (int i = 0; i < 8; i++) {
        float4 v = *(const float4*)(sp + i * 4);
        ushort2 o0, o1;
        o0.x = f2b(v.x); o0.y = f2b(v.y);
        o1.x = f2b(v.z); o1.y = f2b(v.w);
        *(ushort2*)(tp + i * 4) = o0;
        *(ushort2*)(tp + i * 4 + 2) = o1;
    }
    __syncthreads();
    int oc = tid & 63, ch = tid >> 6;
    union { ushort u[32]; uint4 v[4]; } p;
#pragma unroll
    for (int j = 0; j < 32; j++) p.u[j] = T[(ch * 32 + j) * 70 + oc];
    uint4* dp = (uint4*)(dst + (size_t)(c0 + oc) * R + r0 + ch * 32);
    dp[0] = p.v[0]; dp[1] = p.v[1]; dp[2] = p.v[2]; dp[3] = p.v[3];
}

// ---------------- legacy permutation kernel (fallback path only) ----------------
__global__ __launch_bounds__(1024) void build_perm(const int* __restrict__ eids,
                                                   int* __restrict__ tok_sorted,
                                                   int* __restrict__ off,
                                                   int* __restrict__ meta,
                                                   int write_tiles) {
    __shared__ int cnt[EE], cur[EE], offs[EE + 1];
    int tid = threadIdx.x;
    if (tid < EE) cnt[tid] = 0;
    __syncthreads();
    for (int t = tid; t < TT; t += 1024) atomicAdd(&cnt[eids[t]], 1);
    __syncthreads();
    if (tid == 0) {
        int s = 0;
        for (int e = 0; e < EE; e++) { offs[e] = s; s += cnt[e]; }
        offs[EE] = s;
        if (write_tiles) {
            int nt = 0;
            for (int e = 0; e < EE; e++) {
                int c = offs[e + 1] - offs[e];
                for (int m0 = 0; m0 < c; m0 += 128) {
                    meta[16 + nt] = e;
                    meta[96 + nt] = offs[e] + m0;
                    meta[176 + nt] = (c - m0 < 128) ? (c - m0) : 128;
                    nt++;
                }
            }
            meta[0] = nt;
        }
    }
    __syncthreads();
    if (tid < EE) cur[tid] = offs[tid];
    if (tid < EE + 1) off[tid] = offs[tid];
    __syncthreads();
    for (int t = tid; t < TT; t += 1024) {
        int p = atomicAdd(&cur[eids[t]], 1);
        tok_sorted[p] = t;
    }
}

// ---------------- fused prep: perm (block 0) || X cvt || W1^T || W2^T ----------------
__global__ __launch_bounds__(256) void prep(const float* __restrict__ X,
                                            const float* __restrict__ W1,
                                            const float* __restrict__ W2,
                                            const int* __restrict__ eids,
                                            ushort* __restrict__ Xb,
                                            ushort* __restrict__ W1t,
                                            ushort* __restrict__ W2t,
                                            int* __restrict__ tok,
                                            int* __restrict__ off,
                                            int* __restrict__ meta) {
    int id = blockIdx.x;
    int tid = threadIdx.x;
    if (id == 0) {
        __shared__ int cnt[EE], cur[EE], offs[EE + 1];
        if (tid < EE) cnt[tid] = 0;
        __syncthreads();
        for (int t = tid; t < TT; t += 256) atomicAdd(&cnt[eids[t]], 1);
        __syncthreads();
        if (tid == 0) {
            int s = 0;
            for (int e = 0; e < EE; e++) { offs[e] = s; s += cnt[e]; }
            offs[EE] = s;
            int nt = 0;
            for (int e = 0; e < EE; e++) {
                int c = offs[e + 1] - offs[e];
                for (int m0 = 0; m0 < c; m0 += 128) {
                    meta[16 + nt] = e;
                    meta[96 + nt] = offs[e] + m0;
                    meta[176 + nt] = (c - m0 < 128) ? (c - m0) : 128;
                    nt++;
                }
            }
            meta[0] = nt;
        }
        __syncthreads();
        if (tid < EE) cur[tid] = offs[tid];
        if (tid < EE + 1) off[tid] = offs[tid];
        __syncthreads();
        for (int t = tid; t < TT; t += 256) {
            int p = atomicAdd(&cur[eids[t]], 1);
            tok[p] = t;
        }
        return;
    }
    id -= 1;
    if (id < NCVT) {
        // convert 8192 f32 -> bf16, token order (32 elems/thread, contiguous)
        size_t base = (size_t)id * 8192 + (size_t)tid * 32;
        union { ushort u[32]; uint4 v[4]; } o;
#pragma unroll
        for (int i = 0; i < 8; i++) {
            float4 v = *(const float4*)(X + base + i * 4);
            o.u[i * 4 + 0] = f2b(v.x); o.u[i * 4 + 1] = f2b(v.y);
            o.u[i * 4 + 2] = f2b(v.z); o.u[i * 4 + 3] = f2b(v.w);
        }
        uint4* dp = (uint4*)(Xb + base);
        dp[0] = o.v[0]; dp[1] = o.v[1]; dp[2] = o.v[2]; dp[3] = o.v[3];
        return;
    }
    id -= NCVT;
    __shared__ ushort Tt[128 * 70];
    if (id < NXPT) {
        // W1: [HH][II] f32 -> [II][HH] bf16 per expert; 288 tiles/expert (6 r x 48 c)
        int e = id / 288;
        int t = id - e * 288;
        int c0 = (t % 48) * 64, r0 = (t / 48) * 128;
        xpose_tile128(W1 + (size_t)e * HH * II, W1t + (size_t)e * HH * II,
                      HH, II, r0, c0, tid, Tt);
        return;
    }
    id -= NXPT;
    {
        // W2: [II][HH] f32 -> [HH][II] bf16 per expert; 288 tiles/expert (24 r x 12 c)
        int e = id / 288;
        int t = id - e * 288;
        int c0 = (t % 12) * 64, r0 = (t / 12) * 128;
        xpose_tile128(W2 + (size_t)e * II * HH, W2t + (size_t)e * II * HH,
                      II, HH, r0, c0, tid, Tt);
    }
}

// ---------------- grouped GEMM: C = act(A @ B^T [+ bias]) ----------------
// 2-phase double-buffered K-loop (BK=32 cur/next), XOR-swizzled LDS, 128x128 tile,
// 4 blocks/CU (register-exact: 60 VGPR + 64 AGPR = 124 <= 128), XCD-chunked swizzle.
// Per step: issue STAGE(t+1) -> ds_read(t) -> MFMA(t) -> one barrier (vmcnt+lgkm drain).
// GATHER: A rows indirected through tok[] (bf16 X in token order).
// SPLITK: K split; half kh writes f32 partials to outp + kh*TT*NT (no bias).
template<int KT, int NT, bool GELU, bool OUTF32, bool GATHER, int SPLITK>
__global__ __launch_bounds__(256, 4) void gemm_k(const ushort* __restrict__ A,
                                                 const ushort* __restrict__ B,
                                                 const float* __restrict__ bias,
                                                 const int* __restrict__ tok,
                                                 const int* __restrict__ meta,
                                                 void* __restrict__ outp) {
    constexpr int NTN = NT / 128;
    constexpr int NGEMM = MAXT * NTN * SPLITK;
    constexpr int KS = KT / SPLITK;
    int id = blockIdx.x;
    int tid = threadIdx.x;

    __shared__ __attribute__((aligned(16))) char SM[32768];

    // XCD-chunked bijective swizzle (NGEMM % 8 == 0), bx-major decode.
    constexpr int CHUNK = NGEMM >> 3;
    int fid = (id & 7) * CHUNK + (id >> 3);
    int bx = fid / (NTN * SPLITK);
    int rem = fid - bx * (NTN * SPLITK);
    int by = rem / SPLITK;
    int kh = rem - by * SPLITK;

    if (bx >= meta[0]) return;
    int e = meta[16 + bx];
    int start = meta[96 + bx];
    int rows = meta[176 + bx];
    int n0 = by * 128;
    int kbase = kh * KS;

    const ushort* Be = B + (size_t)e * NT * KT;

    ushort* Ab0 = (ushort*)SM;              // [128][32] bf16, step parity 0
    ushort* Ab1 = (ushort*)(SM + 8192);     // parity 1
    ushort* Bb0 = (ushort*)(SM + 16384);
    ushort* Bb1 = (ushort*)(SM + 24576);

    int lane = tid & 63, m = lane & 15, quad = lane >> 4;
    int wv = tid >> 6, wm = wv & 1, wn = wv >> 1;

    // staging: lane covers (row r = tid>>2, phys chunk tid&3) holding src kchunk kcs
    int rA = tid >> 2;
    int kcs = (tid & 3) ^ ((tid >> 3) & 3);
    const ushort *ga0, *ga1;
    if constexpr (GATHER) {
        int i0 = start + rA;       if (i0 > TT - 1) i0 = TT - 1;
        int i1 = start + 64 + rA;  if (i1 > TT - 1) i1 = TT - 1;
        ga0 = A + (size_t)tok[i0] * KT + kbase + kcs * 8;
        ga1 = A + (size_t)tok[i1] * KT + kbase + kcs * 8;
    } else {
        ga0 = A + (size_t)(start + rA) * KT + kbase + kcs * 8;
        ga1 = ga0 + (size_t)64 * KT;
    }
    const ushort* gb0 = Be + (size_t)(n0 + rA) * KT + kbase + kcs * 8;
    const ushort* gb1 = gb0 + (size_t)64 * KT;

    // per-wave glds dest bases (rows 0-63 then 64-127 of each [128][32] buffer)
    ushort* dA0  = Ab0 + wv * 512;  ushort* dA0h = Ab0 + 2048 + wv * 512;
    ushort* dA1  = Ab1 + wv * 512;  ushort* dA1h = Ab1 + 2048 + wv * 512;
    ushort* dB0  = Bb0 + wv * 512;  ushort* dB0h = Bb0 + 2048 + wv * 512;
    ushort* dB1  = Bb1 + wv * 512;  ushort* dB1h = Bb1 + 2048 + wv * 512;

    f32x4 acc[4][4] = {};

    // fragment read offsets (swizzled): qx = quad ^ ((m>>1)&3)
    int qx = quad ^ ((m >> 1) & 3);
    int foA = (wm * 64 + m) * 32 + qx * 8;
    int foB = (wn * 64 + m) * 32 + qx * 8;

    constexpr int NSTEP = KS / 32;
    // prologue: stage step 0 into parity-0
    glds16(ga0, dA0); glds16(ga1, dA0h);
    glds16(gb0, dB0); glds16(gb1, dB0h);
    ga0 += 32; ga1 += 32; gb0 += 32; gb1 += 32;
    __syncthreads();
#pragma unroll 2
    for (int t = 0; t < NSTEP; ++t) {
        bool odd = (t & 1) != 0;
        if (t + 1 < NSTEP) {
            // stage next step into the other parity
            if (odd) { glds16(ga0, dA0); glds16(ga1, dA0h); glds16(gb0, dB0); glds16(gb1, dB0h); }
            else     { glds16(ga0, dA1); glds16(ga1, dA1h); glds16(gb0, dB1); glds16(gb1, dB1h); }
            ga0 += 32; ga1 += 32; gb0 += 32; gb1 += 32;
        }
        const ushort* as = odd ? Ab1 : Ab0;
        const ushort* bs = odd ? Bb1 : Bb0;
        bf16x8 a[4], b[4];
#pragma unroll
        for (int i = 0; i < 4; i++) a[i] = *(const bf16x8*)(as + foA + i * 512);
#pragma unroll
        for (int j = 0; j < 4; j++) b[j] = *(const bf16x8*)(bs + foB + j * 512);
#pragma unroll
        for (int i = 0; i < 4; i++)
#pragma unroll
            for (int j = 0; j < 4; j++)
                acc[i][j] = __builtin_amdgcn_mfma_f32_16x16x32_bf16(a[i], b[j], acc[i][j], 0, 0, 0);
        __syncthreads();   // drains staged vmcnt + all reads of current buffer
    }

    float bv[4];
    if constexpr (GELU) {
        const float* be = bias + (size_t)e * NT;
#pragma unroll
        for (int j = 0; j < 4; j++) bv[j] = be[n0 + wn * 64 + j * 16 + m];
    }

#pragma unroll
    for (int i = 0; i < 4; i++) {
#pragma unroll
        for (int r = 0; r < 4; r++) {
            int row = wm * 64 + i * 16 + quad * 4 + r;
            if (row < rows) {
#pragma unroll
                for (int j = 0; j < 4; j++) {
                    int col = n0 + wn * 64 + j * 16 + m;
                    float v = acc[i][j][r];
                    if (GELU) v = fast_gelu(v + bv[j]);
                    if (OUTF32) ((float*)outp)[(size_t)kh * TT * NT + (size_t)(start + row) * NT + col] = v;
                    else ((ushort*)outp)[(size_t)(start + row) * NT + col] = f2b(v);
                }
            }
        }
    }
}

// ---------------- LayerNorm: sel halves + bias + residual -> out (wave-per-row) ----------------
__global__ __launch_bounds__(256) void ln2_kernel(const float* __restrict__ s0,
                                                  const float* __restrict__ s1,
                                                  const float* __restrict__ X,
                                                  const float* __restrict__ B2,
                                                  const float* __restrict__ gamma,
                                                  const float* __restrict__ beta,
                                                  const int* __restrict__ tok,
                                                  const int* __restrict__ off,
                                                  float* __restrict__ out,
                                                  int halves) {
    int tid = threadIdx.x;
    int wv = tid >> 6, lane = tid & 63;
    int gr = blockIdx.x * 4 + wv;        // sorted-row index
    if (gr >= TT) return;
    int tk = tok[gr];
    int e = 0;
#pragma unroll
    for (int i = 1; i < EE; i++) e += (gr >= off[i]) ? 1 : 0;
    const float* b2 = B2 + (size_t)e * HH;
    int col = lane * 4;
    float vb[12];
    float s = 0.f, s2 = 0.f;
#pragma unroll
    for (int j = 0; j < 3; j++) {
        int c = col + j * 256;
        float4 a = *(const float4*)(s0 + (size_t)gr * HH + c);
        if (halves == 2) {
            float4 a1 = *(const float4*)(s1 + (size_t)gr * HH + c);
            a.x += a1.x; a.y += a1.y; a.z += a1.z; a.w += a1.w;
        }
        float4 xr = *(const float4*)(X + (size_t)tk * HH + c);
        float4 bb = *(const float4*)(b2 + c);
        float t0 = a.x + xr.x + bb.x;
        float t1 = a.y + xr.y + bb.y;
        float t2 = a.z + xr.z + bb.z;
        float t3 = a.w + xr.w + bb.w;
        vb[j * 4 + 0] = t0; vb[j * 4 + 1] = t1; vb[j * 4 + 2] = t2; vb[j * 4 + 3] = t3;
        s += t0 + t1 + t2 + t3;
        s2 += t0 * t0 + t1 * t1 + t2 * t2 + t3 * t3;
    }
#pragma unroll
    for (int o = 1; o < 64; o <<= 1) {
        s += __shfl_xor(s, o);
        s2 += __shfl_xor(s2, o);
    }
    float mu = s * (1.0f / (float)HH);
    float var = s2 * (1.0f / (float)HH) - mu * mu;
    float rs = rsqrtf(var + 1e-12f);
#pragma unroll
    for (int j = 0; j < 3; j++) {
        int c = col + j * 256;
        float4 g4 = *(const float4*)(gamma + c);
        float4 b4 = *(const float4*)(beta + c);
        float4 o4;
        o4.x = (vb[j * 4 + 0] - mu) * rs * g4.x + b4.x;
        o4.y = (vb[j * 4 + 1] - mu) * rs * g4.y + b4.y;
        o4.z = (vb[j * 4 + 2] - mu) * rs * g4.z + b4.z;
        o4.w = (vb[j * 4 + 3] - mu) * rs * g4.w + b4.w;
        *(float4*)(out + (size_t)tk * HH + c) = o4;
    }
}

// ---------------- standalone LayerNorm (fallback path) ----------------
__global__ __launch_bounds__(256) void ln_kernel(const float* __restrict__ sel,
                                                 const float* __restrict__ X,
                                                 const float* __restrict__ gamma,
                                                 const float* __restrict__ beta,
                                                 const int* __restrict__ tok_sorted,
                                                 float* __restrict__ out,
                                                 int add_res) {
    int r = blockIdx.x;
    int tok = tok_sorted[r];
    int tid = threadIdx.x;

    float v[3];
    float s = 0.f, s2 = 0.f;
#pragma unroll
    for (int j = 0; j < 3; j++) {
        int h = tid + j * 256;
        float t = sel[(size_t)r * HH + h];
        if (add_res) t += X[(size_t)tok * HH + h];
        v[j] = t; s += t; s2 += t * t;
    }
#pragma unroll
    for (int o = 32; o > 0; o >>= 1) {
        s += __shfl_down(s, o);
        s2 += __shfl_down(s2, o);
    }
    __shared__ float ws1[4], ws2[4];
    int lane = tid & 63, w = tid >> 6;
    if (lane == 0) { ws1[w] = s; ws2[w] = s2; }
    __syncthreads();
    __shared__ float mu_s, rs_s;
    if (tid == 0) {
        float a = 0.f, b = 0.f;
        for (int i = 0; i < 4; i++) { a += ws1[i]; b += ws2[i]; }
        float mu = a / (float)HH;
        float var = b / (float)HH - mu * mu;
        mu_s = mu;
        rs_s = rsqrtf(var + 1e-12f);
    }
    __syncthreads();
    float mu = mu_s, rs = rs_s;
#pragma unroll
    for (int j = 0; j < 3; j++) {
        int h = tid + j * 256;
        float o = (v[j] - mu) * rs * gamma[h] + beta[h];
        out[(size_t)tok * HH + h] = o;
    }
}

// ================= fallback (small ws) kernels =================
__global__ __launch_bounds__(256) void gemm1_s(const float* __restrict__ X,
                                               const float* __restrict__ W1,
                                               const float* __restrict__ B1,
                                               const int* __restrict__ tok_sorted,
                                               const int* __restrict__ off,
                                               ushort* __restrict__ inter) {
    int slot = blockIdx.x;
    int e = slot >> 7, tile = slot & 127;
    int start = off[e] + (tile << 6);
    int end = off[e + 1];
    if (start >= end) return;
    int rows = end - start; if (rows > 64) rows = 64;
    int n0 = blockIdx.y << 6;
    const float* W1e = W1 + (size_t)e * HH * II;
    __shared__ ushort As[64 * 32];
    __shared__ ushort Bt[64 * 32];
    int tid = threadIdx.x;
    int w = tid >> 6, lane = tid & 63, m = lane & 15, quad = lane >> 4;
    int rrA = tid >> 2, c8A = tid & 3;
    int tokA = tok_sorted[start + (rrA < rows ? rrA : 0)];
    const float* gA = X + (size_t)tokA * HH + c8A * 8;
    int kB = tid >> 3, n8 = tid & 7;
    const float* gB = W1e + (size_t)kB * II + n0 + n8 * 8;
    f32x4 acc[4] = {};
    for (int k0 = 0; k0 < HH; k0 += 32) {
        float4 a0 = *(const float4*)(gA + k0);
        float4 a1 = *(const float4*)(gA + k0 + 4);
        float4 b0 = *(const float4*)(gB + (size_t)k0 * II);
        float4 b1 = *(const float4*)(gB + (size_t)k0 * II + 4);
        __syncthreads();
        union { ushort u[8]; uint4 v; } ta;
        ta.u[0] = f2b(a0.x); ta.u[1] = f2b(a0.y); ta.u[2] = f2b(a0.z); ta.u[3] = f2b(a0.w);
        ta.u[4] = f2b(a1.x); ta.u[5] = f2b(a1.y); ta.u[6] = f2b(a1.z); ta.u[7] = f2b(a1.w);
        *(uint4*)&As[rrA * 32 + c8A * 8] = ta.v;
        float bb[8] = {b0.x, b0.y, b0.z, b0.w, b1.x, b1.y, b1.z, b1.w};
#pragma unroll
        for (int j = 0; j < 8; j++) Bt[(n8 * 8 + j) * 32 + kB] = f2b(bb[j]);
        __syncthreads();
        bf16x8 a = *(const bf16x8*)&As[(w * 16 + m) * 32 + quad * 8];
#pragma unroll
        for (int nb = 0; nb < 4; nb++) {
            bf16x8 b = *(const bf16x8*)&Bt[(nb * 16 + m) * 32 + quad * 8];
            acc[nb] = __builtin_amdgcn_mfma_f32_16x16x32_bf16(a, b, acc[nb], 0, 0, 0);
        }
    }
    const float* b1e = B1 + (size_t)e * II;
#pragma unroll
    for (int nb = 0; nb < 4; nb++) {
        int col = n0 + nb * 16 + m;
        float bias = b1e[col];
#pragma unroll
        for (int r = 0; r < 4; r++) {
            int row = w * 16 + quad * 4 + r;
            if (row < rows) {
                float v = acc[nb][r] + bias;
                inter[(size_t)(start + row) * II + col] = f2b(fast_gelu(v));
            }
        }
    }
}

__global__ __launch_bounds__(256) void gemm2_s(const ushort* __restrict__ inter,
                                               const float* __restrict__ W2,
                                               const float* __restrict__ B2,
                                               const int* __restrict__ off,
                                               float* __restrict__ sel) {
    int slot = blockIdx.x;
    int e = slot >> 7, tile = slot & 127;
    int start = off[e] + (tile << 6);
    int end = off[e + 1];
    if (start >= end) return;
    int rows = end - start; if (rows > 64) rows = 64;
    int n0 = blockIdx.y << 6;
    const float* W2e = W2 + (size_t)e * II * HH;
    __shared__ ushort As[64 * 32];
    __shared__ ushort Bt[64 * 32];
    int tid = threadIdx.x;
    int w = tid >> 6, lane = tid & 63, m = lane & 15, quad = lane >> 4;
    int rrA = tid >> 2, c8A = tid & 3;
    int rA = start + rrA; if (rA > TT - 1) rA = TT - 1;
    const ushort* gA = inter + (size_t)rA * II + c8A * 8;
    int kB = tid >> 3, n8 = tid & 7;
    const float* gB = W2e + (size_t)kB * HH + n0 + n8 * 8;
    f32x4 acc[4] = {};
    for (int k0 = 0; k0 < II; k0 += 32) {
        uint4 av = *(const uint4*)(gA + k0);
        float4 b0 = *(const float4*)(gB + (size_t)k0 * HH);
        float4 b1 = *(const float4*)(gB + (size_t)k0 * HH + 4);
        __syncthreads();
        *(uint4*)&As[rrA * 32 + c8A * 8] = av;
        float bb[8] = {b0.x, b0.y, b0.z, b0.w, b1.x, b1.y, b1.z, b1.w};
#pragma unroll
        for (int j = 0; j < 8; j++) Bt[(n8 * 8 + j) * 32 + kB] = f2b(bb[j]);
        __syncthreads();
        bf16x8 a = *(const bf16x8*)&As[(w * 16 + m) * 32 + quad * 8];
#pragma unroll
        for (int nb = 0; nb < 4; nb++) {
            bf16x8 b = *(const bf16x8*)&Bt[(nb * 16 + m) * 32 + quad * 8];
            acc[nb] = __builtin_amdgcn_mfma_f32_16x16x32_bf16(a, b, acc[nb], 0, 0, 0);
        }
    }
    const float* b2e = B2 + (size_t)e * HH;
#pragma unroll
    for (int nb = 0; nb < 4; nb++) {
        int col = n0 + nb * 16 + m;
        float bias = b2e[col];
#pragma unroll
        for (int r = 0; r < 4; r++) {
            int row = w * 16 + quad * 4 + r;
            if (row < rows) sel[(size_t)(start + row) * HH + col] = acc[nb][r] + bias;
        }
    }
}

extern "C" void kernel_launch(void* const* d_in, const int* in_sizes, int n_in,
                              void* d_out, int out_size, void* d_ws, size_t ws_size,
                              hipStream_t stream) {
    const float* X  = (const float*)d_in[0];
    const float* W1 = (const float*)d_in[1];
    const float* B1 = (const float*)d_in[2];
    const float* W2 = (const float*)d_in[3];
    const float* B2 = (const float*)d_in[4];
    const float* G  = (const float*)d_in[5];
    const float* Bt = (const float*)d_in[6];
    const int* eids = (const int*)d_in[7];
    float* out = (float*)d_out;
    char* ws = (char*)d_ws;

    const size_t XB_OFF    = 34816;
    const size_t XB_SZ     = (size_t)2 * TT * HH;
    const size_t W1T_OFF   = XB_OFF + XB_SZ;
    const size_t W1T_SZ    = (size_t)2 * EE * HH * II;
    const size_t W2T_OFF   = W1T_OFF + W1T_SZ;
    const size_t INTER_OFF = W2T_OFF + W1T_SZ;
    const size_t INTER_SZ  = (size_t)2 * (TT + 128) * II;
    const size_t SEL_OFF   = INTER_OFF + INTER_SZ;
    const size_t SEL_SZ    = (size_t)4 * TT * HH;
    const size_t NEED1     = SEL_OFF + SEL_SZ;          // single-K path
    const size_t NEED2     = NEED1 + SEL_SZ;            // split-K=2 path (extra partial buf)

    if (ws_size >= NEED1) {
        int* off = (int*)ws;
        int* meta = (int*)(ws + 64);
        int* tok = (int*)(ws + 2048);
        ushort* Xb = (ushort*)(ws + XB_OFF);
        ushort* W1t = (ushort*)(ws + W1T_OFF);
        ushort* W2t = (ushort*)(ws + W2T_OFF);
        ushort* inter = (ushort*)(ws + INTER_OFF);
        float* sel = (float*)(ws + SEL_OFF);

        // prep: perm || X convert || W1^T || W2^T (all concurrent in one dispatch)
        prep<<<1 + NCVT + 2 * NXPT, 256, 0, stream>>>(X, W1, W2, eids, Xb, W1t, W2t, tok, off, meta);
        // GEMM1: inter = gelu(Xb @ W1t^T + b1), bf16 out
        gemm_k<HH, II, true, false, true, 1>
            <<<MAXT * (II / 128), 256, 0, stream>>>(Xb, W1t, B1, tok, meta, inter);
        if (ws_size >= NEED2) {
            // GEMM2 split-K=2: f32 partials (no bias); LN sums halves
            gemm_k<II, HH, false, true, false, 2>
                <<<MAXT * (HH / 128) * 2, 256, 0, stream>>>(inter, W2t, B2, tok, meta, sel);
            ln2_kernel<<<TT / 4, 256, 0, stream>>>(sel, sel + (size_t)TT * HH, X, B2, G, Bt,
                                                   tok, off, out, 2);
        } else {
            gemm_k<II, HH, false, true, false, 1>
                <<<MAXT * (HH / 128), 256, 0, stream>>>(inter, W2t, B2, tok, meta, sel);
            ln2_kernel<<<TT / 4, 256, 0, stream>>>(sel, sel, X, B2, G, Bt,
                                                   tok, off, out, 1);
        }
    } else {
        int* off = (int*)ws;
        int* tok = (int*)(ws + 64);
        ushort* inter = (ushort*)(ws + 64 + 4 * TT);
        float* sel = (float*)(ws + 64 + 4 * TT + (size_t)2 * TT * II);
        build_perm<<<1, 1024, 0, stream>>>(eids, tok, off, off, 0);
        gemm1_s<<<dim3(EE * 128, II / 64), 256, 0, stream>>>(X, W1, B1, tok, off, inter);
        gemm2_s<<<dim3(EE * 128, HH / 64), 256, 0, stream>>>(inter, W2, B2, off, sel);
        ln_kernel<<<TT, 256, 0, stream>>>(sel, X, G, Bt, tok, out, 1);
    }
}

// Round 7
// 354.281 us; speedup vs baseline: 1.0752x; 1.0752x over previous
//
#include <hip/hip_runtime.h>
#include <math.h>

#define TT 8192
#define HH 768
#define II 3072
#define EE 8
#define MAXT 72
#define NCVT 3072
#define NXP 4608   // 64x64 transpose tiles per weight tensor: 8 * (768/64)*(3072/64)

typedef short bf16x8 __attribute__((ext_vector_type(8)));
typedef float f32x4 __attribute__((ext_vector_type(4)));

__device__ __forceinline__ ushort f2b(float f) {
    union { float f; unsigned int i; } x; x.f = f;
    unsigned int r = x.i + 0x7fffu + ((x.i >> 16) & 1u);
    return (ushort)(r >> 16);
}

__device__ __forceinline__ void glds16(const ushort* g, ushort* l) {
    __builtin_amdgcn_global_load_lds(
        (const __attribute__((address_space(1))) void*)g,
        (__attribute__((address_space(3))) void*)l, 16, 0, 0);
}

// A&S 7.1.26 erf (max abs err 1.5e-7) -> exact-GELU
__device__ __forceinline__ float fast_gelu(float v) {
    float x = v * 0.70710678118654752f;
    float ax = fabsf(x);
    float t = __builtin_amdgcn_rcpf(__builtin_fmaf(0.3275911f, ax, 1.0f));
    float p = __builtin_fmaf(t, 1.061405429f, -1.453152027f);
    p = __builtin_fmaf(t, p, 1.421413741f);
    p = __builtin_fmaf(t, p, -0.284496736f);
    p = __builtin_fmaf(t, p, 0.254829592f);
    p = p * t;
    float e = __expf(-ax * ax);
    float erf_abs = 1.0f - p * e;
    float er = (x < 0.0f) ? -erf_abs : erf_abs;
    return 0.5f * v * (1.0f + er);
}

// ---- 64x64 transpose+convert tile: src f32 [.][C] -> dst bf16 [C][R] ----
// Per-instruction-wide lane maps:
//   load:  16 lanes/src-row x float4  -> wave reads 4 rows x 256B contiguous
//   store:  8 lanes/dst-row x uint4   -> wave writes 8 rows x 128B contiguous
// LDS float[64][65]: both phases exactly 2-way bank aliasing (free).
__device__ __forceinline__ void xpose_tile(const float* __restrict__ src,
                                           ushort* __restrict__ dst,
                                           int R, int C, int r0, int c0,
                                           int tid, float* __restrict__ Tm) {
    int lane16 = tid & 15, rowg = tid >> 4;      // 16 rows per pass
#pragma unroll
    for (int p = 0; p < 4; p++) {
        int lr = p * 16 + rowg;
        float4 v = *(const float4*)(src + (size_t)(r0 + lr) * C + c0 + lane16 * 4);
        float* tp = Tm + lr * 65 + lane16 * 4;
        tp[0] = v.x; tp[1] = v.y; tp[2] = v.z; tp[3] = v.w;
    }
    __syncthreads();
    int lane8 = tid & 7, ocg = tid >> 3;          // 32 dst rows per pass
#pragma unroll
    for (int p = 0; p < 2; p++) {
        int oc = p * 32 + ocg;
        union { ushort u[8]; uint4 v; } pk;
#pragma unroll
        for (int j = 0; j < 8; j++) pk.u[j] = f2b(Tm[(lane8 * 8 + j) * 65 + oc]);
        *(uint4*)(dst + (size_t)(c0 + oc) * R + r0 + lane8 * 8) = pk.v;
    }
}

// ---------------- legacy permutation kernel (fallback path only) ----------------
__global__ __launch_bounds__(1024) void build_perm(const int* __restrict__ eids,
                                                   int* __restrict__ tok_sorted,
                                                   int* __restrict__ off,
                                                   int* __restrict__ meta,
                                                   int write_tiles) {
    __shared__ int cnt[EE], cur[EE], offs[EE + 1];
    int tid = threadIdx.x;
    if (tid < EE) cnt[tid] = 0;
    __syncthreads();
    for (int t = tid; t < TT; t += 1024) atomicAdd(&cnt[eids[t]], 1);
    __syncthreads();
    if (tid == 0) {
        int s = 0;
        for (int e = 0; e < EE; e++) { offs[e] = s; s += cnt[e]; }
        offs[EE] = s;
        if (write_tiles) {
            int nt = 0;
            for (int e = 0; e < EE; e++) {
                int c = offs[e + 1] - offs[e];
                for (int m0 = 0; m0 < c; m0 += 128) {
                    meta[16 + nt] = e;
                    meta[96 + nt] = offs[e] + m0;
                    meta[176 + nt] = (c - m0 < 128) ? (c - m0) : 128;
                    nt++;
                }
            }
            meta[0] = nt;
        }
    }
    __syncthreads();
    if (tid < EE) cur[tid] = offs[tid];
    if (tid < EE + 1) off[tid] = offs[tid];
    __syncthreads();
    for (int t = tid; t < TT; t += 1024) {
        int p = atomicAdd(&cur[eids[t]], 1);
        tok_sorted[p] = t;
    }
}

// ---------------- fused prep: perm (block 0) || X cvt || W1^T || W2^T ----------------
__global__ __launch_bounds__(256) void prep(const float* __restrict__ X,
                                            const float* __restrict__ W1,
                                            const float* __restrict__ W2,
                                            const int* __restrict__ eids,
                                            ushort* __restrict__ Xb,
                                            ushort* __restrict__ W1t,
                                            ushort* __restrict__ W2t,
                                            int* __restrict__ tok,
                                            int* __restrict__ off,
                                            int* __restrict__ meta) {
    int id = blockIdx.x;
    int tid = threadIdx.x;
    if (id == 0) {
        __shared__ int cnt[EE], cur[EE], offs[EE + 1];
        if (tid < EE) cnt[tid] = 0;
        __syncthreads();
        for (int t = tid; t < TT; t += 256) atomicAdd(&cnt[eids[t]], 1);
        __syncthreads();
        if (tid == 0) {
            int s = 0;
            for (int e = 0; e < EE; e++) { offs[e] = s; s += cnt[e]; }
            offs[EE] = s;
            int nt = 0;
            for (int e = 0; e < EE; e++) {
                int c = offs[e + 1] - offs[e];
                for (int m0 = 0; m0 < c; m0 += 128) {
                    meta[16 + nt] = e;
                    meta[96 + nt] = offs[e] + m0;
                    meta[176 + nt] = (c - m0 < 128) ? (c - m0) : 128;
                    nt++;
                }
            }
            meta[0] = nt;
        }
        __syncthreads();
        if (tid < EE) cur[tid] = offs[tid];
        if (tid < EE + 1) off[tid] = offs[tid];
        __syncthreads();
        for (int t = tid; t < TT; t += 256) {
            int p = atomicAdd(&cur[eids[t]], 1);
            tok[p] = t;
        }
        return;
    }
    id -= 1;
    if (id < NCVT) {
        // convert 2048 f32 -> bf16, token order (no gather)
        size_t base = (size_t)id * 2048 + (size_t)tid * 8;
        float4 v0 = *(const float4*)(X + base);
        float4 v1 = *(const float4*)(X + base + 4);
        union { ushort u[8]; uint4 v; } o;
        o.u[0] = f2b(v0.x); o.u[1] = f2b(v0.y); o.u[2] = f2b(v0.z); o.u[3] = f2b(v0.w);
        o.u[4] = f2b(v1.x); o.u[5] = f2b(v1.y); o.u[6] = f2b(v1.z); o.u[7] = f2b(v1.w);
        *(uint4*)(Xb + base) = o.v;
        return;
    }
    id -= NCVT;
    __shared__ float Tt[64 * 65];
    if (id < NXP) {
        // W1: [HH][II] f32 -> [II][HH] bf16 per expert; 576 tiles/expert
        int e = id / 576;
        int t = id - e * 576;
        int ctiles = II >> 6;                 // 48
        int c0 = (t % ctiles) << 6, r0 = (t / ctiles) << 6;
        xpose_tile(W1 + (size_t)e * HH * II, W1t + (size_t)e * HH * II,
                   HH, II, r0, c0, tid, Tt);
        return;
    }
    id -= NXP;
    {
        // W2: [II][HH] f32 -> [HH][II] bf16 per expert
        int e = id / 576;
        int t = id - e * 576;
        int ctiles = HH >> 6;                 // 12
        int c0 = (t % ctiles) << 6, r0 = (t / ctiles) << 6;
        xpose_tile(W2 + (size_t)e * II * HH, W2t + (size_t)e * II * HH,
                   II, HH, r0, c0, tid, Tt);
    }
}

// ---------------- grouped GEMM: C = act(A @ B^T [+ bias]) ----------------
// BK=64, XOR-swizzled LDS, 128x128 tile, 4 blocks/CU (no-spill register point),
// XCD-chunked swizzle.
// GATHER: A rows indirected through tok[] (bf16 X in token order).
// SPLITK: K split; half kh writes f32 partials to outp + kh*TT*NT (no bias).
// GELU path (GEMM1) adds bias then gelu, writes bf16.
template<int KT, int NT, bool GELU, bool OUTF32, bool GATHER, int SPLITK>
__global__ __launch_bounds__(256, 4) void gemm_k(const ushort* __restrict__ A,
                                                 const ushort* __restrict__ B,
                                                 const float* __restrict__ bias,
                                                 const int* __restrict__ tok,
                                                 const int* __restrict__ meta,
                                                 void* __restrict__ outp) {
    constexpr int NTN = NT / 128;
    constexpr int NGEMM = MAXT * NTN * SPLITK;
    constexpr int KS = KT / SPLITK;
    int id = blockIdx.x;
    int tid = threadIdx.x;

    __shared__ __attribute__((aligned(16))) char SM[32768];

    // XCD-chunked bijective swizzle (NGEMM % 8 == 0), bx-major decode.
    constexpr int CHUNK = NGEMM >> 3;
    int fid = (id & 7) * CHUNK + (id >> 3);
    int bx = fid / (NTN * SPLITK);
    int rem = fid - bx * (NTN * SPLITK);
    int by = rem / SPLITK;
    int kh = rem - by * SPLITK;

    if (bx >= meta[0]) return;
    int e = meta[16 + bx];
    int start = meta[96 + bx];
    int rows = meta[176 + bx];
    int n0 = by * 128;
    int kbase = kh * KS;

    const ushort* Be = B + (size_t)e * NT * KT;

    ushort* As0 = (ushort*)SM;
    ushort* As1 = (ushort*)(SM + 8192);
    ushort* Bs0 = (ushort*)(SM + 16384);
    ushort* Bs1 = (ushort*)(SM + 24576);

    int lane = tid & 63, m = lane & 15, quad = lane >> 4;
    int wv = tid >> 6, wm = wv & 1, wn = wv >> 1;

    // staging: slot s holds (row r = s>>2, chunk c = s&3), storing src kchunk c ^ ((r>>1)&3)
    int rA = tid >> 2;
    int kcs = (tid & 3) ^ ((tid >> 3) & 3);
    const ushort *ga0, *ga1;
    if constexpr (GATHER) {
        int i0 = start + rA;       if (i0 > TT - 1) i0 = TT - 1;
        int i1 = start + 64 + rA;  if (i1 > TT - 1) i1 = TT - 1;
        ga0 = A + (size_t)tok[i0] * KT + kbase + kcs * 8;
        ga1 = A + (size_t)tok[i1] * KT + kbase + kcs * 8;
    } else {
        ga0 = A + (size_t)(start + rA) * KT + kbase + kcs * 8;
        ga1 = ga0 + (size_t)64 * KT;
    }
    const ushort* gb0 = Be + (size_t)(n0 + rA) * KT + kbase + kcs * 8;
    const ushort* gb1 = gb0 + (size_t)64 * KT;
    ushort* dA0a = As0 + wv * 512;
    ushort* dA0b = As0 + 2048 + wv * 512;
    ushort* dB0a = Bs0 + wv * 512;
    ushort* dB0b = Bs0 + 2048 + wv * 512;
    ushort* dA1a = As1 + wv * 512;
    ushort* dA1b = As1 + 2048 + wv * 512;
    ushort* dB1a = Bs1 + wv * 512;
    ushort* dB1b = Bs1 + 2048 + wv * 512;

    f32x4 acc[4][4] = {};

    // fragment read offsets (swizzled): qx = quad ^ ((m>>1)&3)
    int qx = quad ^ ((m >> 1) & 3);
    int foA = (wm * 64 + m) * 32 + qx * 8;
    int foB = (wn * 64 + m) * 32 + qx * 8;

    for (int k0 = 0; k0 < KS; k0 += 64) {
        __syncthreads();
        glds16(ga0, dA0a);
        glds16(ga1, dA0b);
        glds16(gb0, dB0a);
        glds16(gb1, dB0b);
        glds16(ga0 + 32, dA1a);
        glds16(ga1 + 32, dA1b);
        glds16(gb0 + 32, dB1a);
        glds16(gb1 + 32, dB1b);
        ga0 += 64; ga1 += 64; gb0 += 64; gb1 += 64;
        __syncthreads();
#pragma unroll
        for (int s = 0; s < 2; s++) {
            const ushort* as = s ? As1 : As0;
            const ushort* bs = s ? Bs1 : Bs0;
            bf16x8 a[4], b[4];
#pragma unroll
            for (int i = 0; i < 4; i++) a[i] = *(const bf16x8*)(as + foA + i * 16 * 32);
#pragma unroll
            for (int j = 0; j < 4; j++) b[j] = *(const bf16x8*)(bs + foB + j * 16 * 32);
#pragma unroll
            for (int i = 0; i < 4; i++)
#pragma unroll
                for (int j = 0; j < 4; j++)
                    acc[i][j] = __builtin_amdgcn_mfma_f32_16x16x32_bf16(a[i], b[j], acc[i][j], 0, 0, 0);
        }
    }

    float bv[4];
    if constexpr (GELU) {
        const float* be = bias + (size_t)e * NT;
#pragma unroll
        for (int j = 0; j < 4; j++) bv[j] = be[n0 + wn * 64 + j * 16 + m];
    }

#pragma unroll
    for (int i = 0; i < 4; i++) {
#pragma unroll
        for (int r = 0; r < 4; r++) {
            int row = wm * 64 + i * 16 + quad * 4 + r;
            if (row < rows) {
#pragma unroll
                for (int j = 0; j < 4; j++) {
                    int col = n0 + wn * 64 + j * 16 + m;
                    float v = acc[i][j][r];
                    if (GELU) v = fast_gelu(v + bv[j]);
                    if (OUTF32) ((float*)outp)[(size_t)kh * TT * NT + (size_t)(start + row) * NT + col] = v;
                    else ((ushort*)outp)[(size_t)(start + row) * NT + col] = f2b(v);
                }
            }
        }
    }
}

// ---------------- LayerNorm: sel halves + bias + residual -> out (wave-per-row) ----------------
__global__ __launch_bounds__(256) void ln2_kernel(const float* __restrict__ s0,
                                                  const float* __restrict__ s1,
                                                  const float* __restrict__ X,
                                                  const float* __restrict__ B2,
                                                  const float* __restrict__ gamma,
                                                  const float* __restrict__ beta,
                                                  const int* __restrict__ tok,
                                                  const int* __restrict__ off,
                                                  float* __restrict__ out,
                                                  int halves) {
    int tid = threadIdx.x;
    int wv = tid >> 6, lane = tid & 63;
    int gr = blockIdx.x * 4 + wv;        // sorted-row index
    if (gr >= TT) return;
    int tk = tok[gr];
    int e = 0;
#pragma unroll
    for (int i = 1; i < EE; i++) e += (gr >= off[i]) ? 1 : 0;
    const float* b2 = B2 + (size_t)e * HH;
    int col = lane * 4;
    float vb[12];
    float s = 0.f, s2 = 0.f;
#pragma unroll
    for (int j = 0; j < 3; j++) {
        int c = col + j * 256;
        float4 a = *(const float4*)(s0 + (size_t)gr * HH + c);
        if (halves == 2) {
            float4 a1 = *(const float4*)(s1 + (size_t)gr * HH + c);
            a.x += a1.x; a.y += a1.y; a.z += a1.z; a.w += a1.w;
        }
        float4 xr = *(const float4*)(X + (size_t)tk * HH + c);
        float4 bb = *(const float4*)(b2 + c);
        float t0 = a.x + xr.x + bb.x;
        float t1 = a.y + xr.y + bb.y;
        float t2 = a.z + xr.z + bb.z;
        float t3 = a.w + xr.w + bb.w;
        vb[j * 4 + 0] = t0; vb[j * 4 + 1] = t1; vb[j * 4 + 2] = t2; vb[j * 4 + 3] = t3;
        s += t0 + t1 + t2 + t3;
        s2 += t0 * t0 + t1 * t1 + t2 * t2 + t3 * t3;
    }
#pragma unroll
    for (int o = 1; o < 64; o <<= 1) {
        s += __shfl_xor(s, o);
        s2 += __shfl_xor(s2, o);
    }
    float mu = s * (1.0f / (float)HH);
    float var = s2 * (1.0f / (float)HH) - mu * mu;
    float rs = rsqrtf(var + 1e-12f);
#pragma unroll
    for (int j = 0; j < 3; j++) {
        int c = col + j * 256;
        float4 g4 = *(const float4*)(gamma + c);
        float4 b4 = *(const float4*)(beta + c);
        float4 o4;
        o4.x = (vb[j * 4 + 0] - mu) * rs * g4.x + b4.x;
        o4.y = (vb[j * 4 + 1] - mu) * rs * g4.y + b4.y;
        o4.z = (vb[j * 4 + 2] - mu) * rs * g4.z + b4.z;
        o4.w = (vb[j * 4 + 3] - mu) * rs * g4.w + b4.w;
        *(float4*)(out + (size_t)tk * HH + c) = o4;
    }
}

// ---------------- standalone LayerNorm (fallback path) ----------------
__global__ __launch_bounds__(256) void ln_kernel(const float* __restrict__ sel,
                                                 const float* __restrict__ X,
                                                 const float* __restrict__ gamma,
                                                 const float* __restrict__ beta,
                                                 const int* __restrict__ tok_sorted,
                                                 float* __restrict__ out,
                                                 int add_res) {
    int r = blockIdx.x;
    int tok = tok_sorted[r];
    int tid = threadIdx.x;

    float v[3];
    float s = 0.f, s2 = 0.f;
#pragma unroll
    for (int j = 0; j < 3; j++) {
        int h = tid + j * 256;
        float t = sel[(size_t)r * HH + h];
        if (add_res) t += X[(size_t)tok * HH + h];
        v[j] = t; s += t; s2 += t * t;
    }
#pragma unroll
    for (int o = 32; o > 0; o >>= 1) {
        s += __shfl_down(s, o);
        s2 += __shfl_down(s2, o);
    }
    __shared__ float ws1[4], ws2[4];
    int lane = tid & 63, w = tid >> 6;
    if (lane == 0) { ws1[w] = s; ws2[w] = s2; }
    __syncthreads();
    __shared__ float mu_s, rs_s;
    if (tid == 0) {
        float a = 0.f, b = 0.f;
        for (int i = 0; i < 4; i++) { a += ws1[i]; b += ws2[i]; }
        float mu = a / (float)HH;
        float var = b / (float)HH - mu * mu;
        mu_s = mu;
        rs_s = rsqrtf(var + 1e-12f);
    }
    __syncthreads();
    float mu = mu_s, rs = rs_s;
#pragma unroll
    for (int j = 0; j < 3; j++) {
        int h = tid + j * 256;
        float o = (v[j] - mu) * rs * gamma[h] + beta[h];
        out[(size_t)tok * HH + h] = o;
    }
}

// ================= fallback (small ws) kernels =================
__global__ __launch_bounds__(256) void gemm1_s(const float* __restrict__ X,
                                               const float* __restrict__ W1,
                                               const float* __restrict__ B1,
                                               const int* __restrict__ tok_sorted,
                                               const int* __restrict__ off,
                                               ushort* __restrict__ inter) {
    int slot = blockIdx.x;
    int e = slot >> 7, tile = slot & 127;
    int start = off[e] + (tile << 6);
    int end = off[e + 1];
    if (start >= end) return;
    int rows = end - start; if (rows > 64) rows = 64;
    int n0 = blockIdx.y << 6;
    const float* W1e = W1 + (size_t)e * HH * II;
    __shared__ ushort As[64 * 32];
    __shared__ ushort Bt[64 * 32];
    int tid = threadIdx.x;
    int w = tid >> 6, lane = tid & 63, m = lane & 15, quad = lane >> 4;
    int rrA = tid >> 2, c8A = tid & 3;
    int tokA = tok_sorted[start + (rrA < rows ? rrA : 0)];
    const float* gA = X + (size_t)tokA * HH + c8A * 8;
    int kB = tid >> 3, n8 = tid & 7;
    const float* gB = W1e + (size_t)kB * II + n0 + n8 * 8;
    f32x4 acc[4] = {};
    for (int k0 = 0; k0 < HH; k0 += 32) {
        float4 a0 = *(const float4*)(gA + k0);
        float4 a1 = *(const float4*)(gA + k0 + 4);
        float4 b0 = *(const float4*)(gB + (size_t)k0 * II);
        float4 b1 = *(const float4*)(gB + (size_t)k0 * II + 4);
        __syncthreads();
        union { ushort u[8]; uint4 v; } ta;
        ta.u[0] = f2b(a0.x); ta.u[1] = f2b(a0.y); ta.u[2] = f2b(a0.z); ta.u[3] = f2b(a0.w);
        ta.u[4] = f2b(a1.x); ta.u[5] = f2b(a1.y); ta.u[6] = f2b(a1.z); ta.u[7] = f2b(a1.w);
        *(uint4*)&As[rrA * 32 + c8A * 8] = ta.v;
        float bb[8] = {b0.x, b0.y, b0.z, b0.w, b1.x, b1.y, b1.z, b1.w};
#pragma unroll
        for (int j = 0; j < 8; j++) Bt[(n8 * 8 + j) * 32 + kB] = f2b(bb[j]);
        __syncthreads();
        bf16x8 a = *(const bf16x8*)&As[(w * 16 + m) * 32 + quad * 8];
#pragma unroll
        for (int nb = 0; nb < 4; nb++) {
            bf16x8 b = *(const bf16x8*)&Bt[(nb * 16 + m) * 32 + quad * 8];
            acc[nb] = __builtin_amdgcn_mfma_f32_16x16x32_bf16(a, b, acc[nb], 0, 0, 0);
        }
    }
    const float* b1e = B1 + (size_t)e * II;
#pragma unroll
    for (int nb = 0; nb < 4; nb++) {
        int col = n0 + nb * 16 + m;
        float bias = b1e[col];
#pragma unroll
        for (int r = 0; r < 4; r++) {
            int row = w * 16 + quad * 4 + r;
            if (row < rows) {
                float v = acc[nb][r] + bias;
                inter[(size_t)(start + row) * II + col] = f2b(fast_gelu(v));
            }
        }
    }
}

__global__ __launch_bounds__(256) void gemm2_s(const ushort* __restrict__ inter,
                                               const float* __restrict__ W2,
                                               const float* __restrict__ B2,
                                               const int* __restrict__ off,
                                               float* __restrict__ sel) {
    int slot = blockIdx.x;
    int e = slot >> 7, tile = slot & 127;
    int start = off[e] + (tile << 6);
    int end = off[e + 1];
    if (start >= end) return;
    int rows = end - start; if (rows > 64) rows = 64;
    int n0 = blockIdx.y << 6;
    const float* W2e = W2 + (size_t)e * II * HH;
    __shared__ ushort As[64 * 32];
    __shared__ ushort Bt[64 * 32];
    int tid = threadIdx.x;
    int w = tid >> 6, lane = tid & 63, m = lane & 15, quad = lane >> 4;
    int rrA = tid >> 2, c8A = tid & 3;
    int rA = start + rrA; if (rA > TT - 1) rA = TT - 1;
    const ushort* gA = inter + (size_t)rA * II + c8A * 8;
    int kB = tid >> 3, n8 = tid & 7;
    const float* gB = W2e + (size_t)kB * HH + n0 + n8 * 8;
    f32x4 acc[4] = {};
    for (int k0 = 0; k0 < II; k0 += 32) {
        uint4 av = *(const uint4*)(gA + k0);
        float4 b0 = *(const float4*)(gB + (size_t)k0 * HH);
        float4 b1 = *(const float4*)(gB + (size_t)k0 * HH + 4);
        __syncthreads();
        *(uint4*)&As[rrA * 32 + c8A * 8] = av;
        float bb[8] = {b0.x, b0.y, b0.z, b0.w, b1.x, b1.y, b1.z, b1.w};
#pragma unroll
        for (int j = 0; j < 8; j++) Bt[(n8 * 8 + j) * 32 + kB] = f2b(bb[j]);
        __syncthreads();
        bf16x8 a = *(const bf16x8*)&As[(w * 16 + m) * 32 + quad * 8];
#pragma unroll
        for (int nb = 0; nb < 4; nb++) {
            bf16x8 b = *(const bf16x8*)&Bt[(nb * 16 + m) * 32 + quad * 8];
            acc[nb] = __builtin_amdgcn_mfma_f32_16x16x32_bf16(a, b, acc[nb], 0, 0, 0);
        }
    }
    const float* b2e = B2 + (size_t)e * HH;
#pragma unroll
    for (int nb = 0; nb < 4; nb++) {
        int col = n0 + nb * 16 + m;
        float bias = b2e[col];
#pragma unroll
        for (int r = 0; r < 4; r++) {
            int row = w * 16 + quad * 4 + r;
            if (row < rows) sel[(size_t)(start + row) * HH + col] = acc[nb][r] + bias;
        }
    }
}

extern "C" void kernel_launch(void* const* d_in, const int* in_sizes, int n_in,
                              void* d_out, int out_size, void* d_ws, size_t ws_size,
                              hipStream_t stream) {
    const float* X  = (const float*)d_in[0];
    const float* W1 = (const float*)d_in[1];
    const float* B1 = (const float*)d_in[2];
    const float* W2 = (const float*)d_in[3];
    const float* B2 = (const float*)d_in[4];
    const float* G  = (const float*)d_in[5];
    const float* Bt = (const float*)d_in[6];
    const int* eids = (const int*)d_in[7];
    float* out = (float*)d_out;
    char* ws = (char*)d_ws;

    const size_t XB_OFF    = 34816;
    const size_t XB_SZ     = (size_t)2 * TT * HH;
    const size_t W1T_OFF   = XB_OFF + XB_SZ;
    const size_t W1T_SZ    = (size_t)2 * EE * HH * II;
    const size_t W2T_OFF   = W1T_OFF + W1T_SZ;
    const size_t INTER_OFF = W2T_OFF + W1T_SZ;
    const size_t INTER_SZ  = (size_t)2 * (TT + 128) * II;
    const size_t SEL_OFF   = INTER_OFF + INTER_SZ;
    const size_t SEL_SZ    = (size_t)4 * TT * HH;
    const size_t NEED1     = SEL_OFF + SEL_SZ;          // single-K path
    const size_t NEED2     = NEED1 + SEL_SZ;            // split-K=2 path (extra partial buf)

    if (ws_size >= NEED1) {
        int* off = (int*)ws;
        int* meta = (int*)(ws + 64);
        int* tok = (int*)(ws + 2048);
        ushort* Xb = (ushort*)(ws + XB_OFF);
        ushort* W1t = (ushort*)(ws + W1T_OFF);
        ushort* W2t = (ushort*)(ws + W2T_OFF);
        ushort* inter = (ushort*)(ws + INTER_OFF);
        float* sel = (float*)(ws + SEL_OFF);

        // prep: perm || X convert || W1^T || W2^T (all concurrent in one dispatch)
        prep<<<1 + NCVT + 2 * NXP, 256, 0, stream>>>(X, W1, W2, eids, Xb, W1t, W2t, tok, off, meta);
        // GEMM1: inter = gelu(Xb @ W1t^T + b1), bf16 out
        gemm_k<HH, II, true, false, true, 1>
            <<<MAXT * (II / 128), 256, 0, stream>>>(Xb, W1t, B1, tok, meta, inter);
        if (ws_size >= NEED2) {
            // GEMM2 split-K=2: f32 partials (no bias); LN sums halves
            gemm_k<II, HH, false, true, false, 2>
                <<<MAXT * (HH / 128) * 2, 256, 0, stream>>>(inter, W2t, B2, tok, meta, sel);
            ln2_kernel<<<TT / 4, 256, 0, stream>>>(sel, sel + (size_t)TT * HH, X, B2, G, Bt,
                                                   tok, off, out, 2);
        } else {
            gemm_k<II, HH, false, true, false, 1>
                <<<MAXT * (HH / 128), 256, 0, stream>>>(inter, W2t, B2, tok, meta, sel);
            ln2_kernel<<<TT / 4, 256, 0, stream>>>(sel, sel, X, B2, G, Bt,
                                                   tok, off, out, 1);
        }
    } else {
        int* off = (int*)ws;
        int* tok = (int*)(ws + 64);
        ushort* inter = (ushort*)(ws + 64 + 4 * TT);
        float* sel = (float*)(ws + 64 + 4 * TT + (size_t)2 * TT * II);
        build_perm<<<1, 1024, 0, stream>>>(eids, tok, off, off, 0);
        gemm1_s<<<dim3(EE * 128, II / 64), 256, 0, stream>>>(X, W1, B1, tok, off, inter);
        gemm2_s<<<dim3(EE * 128, HH / 64), 256, 0, stream>>>(inter, W2, B2, off, sel);
        ln_kernel<<<TT, 256, 0, stream>>>(sel, X, G, Bt, tok, out, 1);
    }
}